// Round 16
// baseline (111.218 us; speedup 1.0000x reference)
//
#include <hip/hip_runtime.h>
#include <stdint.h>

#define BB 8
#define NN 262144
#define KSEL 6000
#define KPAD2 6144
#define NW2 24               // 24 words of 256 boxes
#define PROP 1000
#define NMS_THR 0.7f
#define CAND_CAP 8192
#define BPB 64               // blocks per batch for hist/compact (4096 items each)
#define STAGE_CAP 768
#define MAT_U64_PB 282624ull // sum_{W=1..23} 256*W rows * 4 u64 = 512*23*24
#define DIAG_U64_PB 24576ull // 24*256*4

// ---------- helpers ----------
__device__ __forceinline__ unsigned long long shfl_xor_u64(unsigned long long v, int m) {
    unsigned lo = (unsigned)v, hi = (unsigned)(v >> 32);
    lo = __shfl_xor(lo, m);
    hi = __shfl_xor(hi, m);
    return ((unsigned long long)hi << 32) | lo;
}
__device__ __forceinline__ uint64_t rdfl64(uint64_t v) {
    uint32_t lo = __builtin_amdgcn_readfirstlane((uint32_t)v);
    uint32_t hi = __builtin_amdgcn_readfirstlane((uint32_t)(v >> 32));
    return ((uint64_t)hi << 32) | lo;
}
__device__ __forceinline__ uint64_t rdlane64(uint64_t v, uint32_t l) {
    uint32_t lo = __builtin_amdgcn_readlane((uint32_t)v, l);
    uint32_t hi = __builtin_amdgcn_readlane((uint32_t)(v >> 32), l);
    return ((uint64_t)hi << 32) | lo;
}

// Exact replacement for RN(inter/den) > 0.7f (den > 0 always):
//   RN(q) > c  <=>  q >= M, M = c + 2^-25 (midpoint; tie rounds to even = c_next > c).
//   M has 25-bit significand, den 24 bits -> M*den exact in f64; comparison exact.
__device__ __forceinline__ uint32_t sup_bit(const float4 bi, float ai, const float4 bj, float aj) {
    float y1 = fmaxf(bi.x, bj.x), x1 = fmaxf(bi.y, bj.y);
    float y2 = fminf(bi.z, bj.z), x2 = fminf(bi.w, bj.w);
    float inter = __fmul_rn(fmaxf(__fsub_rn(y2, y1), 0.f), fmaxf(__fsub_rn(x2, x1), 0.f));
    float den = __fadd_rn(__fsub_rn(__fadd_rn(ai, aj), inter), 1e-10f);
    const double MSUP = 23488103.0 / 33554432.0;   // 0.7f + 2^-25, exact
    return (double)inter >= MSUP * (double)den;
}

__device__ __forceinline__ uint32_t score_bin(float sc) {
    uint32_t u = (uint32_t)(sc * 16777216.0f);
    u = u > 16777215u ? 16777215u : u;
    return u >> 16;
}

// ---------- K1: per-block histogram -> bhist[b][64][256] (plain stores, no zeroing) ----------
__global__ void k_hist(const float4* __restrict__ probs, uint32_t* __restrict__ bhist,
                       uint32_t* __restrict__ cnt, uint32_t* __restrict__ ncount,
                       uint32_t* __restrict__ ndone) {
    __shared__ uint32_t lh[256];
    int blk = blockIdx.x;
    int b = blk >> 6;
    int t = threadIdx.x;
    lh[t] = 0u;
    if (blk == 0 && t < BB) { cnt[t] = 0u; ncount[t] = 0u; ndone[t] = 0u; }
    __syncthreads();
    size_t fbase = ((size_t)b * (NN / 2)) + (size_t)(blk & 63) * 2048;
#pragma unroll
    for (int k = 0; k < 8; ++k) {
        float4 v = probs[fbase + k * 256 + t];
        atomicAdd(&lh[score_bin(v.y)], 1u);
        atomicAdd(&lh[score_bin(v.w)], 1u);
    }
    __syncthreads();
    bhist[((size_t)b << 14) + ((size_t)(blk & 63) << 8) + t] = lh[t];
}

// ---------- K3: compact candidates (threshold derived from bhist), block-aggregated ----------
__global__ void k_compact(const float4* __restrict__ probs, const uint32_t* __restrict__ bhist,
                          uint32_t* __restrict__ cnt, uint64_t* __restrict__ cand) {
    __shared__ uint64_t stage[STAGE_CAP];
    __shared__ uint32_t lh[256];
    __shared__ uint32_t s_bst, lcnt, lbase;
    int blk = blockIdx.x;
    int b = blk >> 6;
    int t = threadIdx.x;
    // batch histogram = sum of the 64 per-block rows
    {
        const uint32_t* bh = bhist + ((size_t)b << 14);
        uint32_t s = 0;
#pragma unroll 8
        for (int k = 0; k < 64; ++k) s += bh[(k << 8) + t];
        lh[t] = s;
    }
    if (t == 0) lcnt = 0u;
    __syncthreads();
    if (t == 0) {
        uint32_t cum = 0; uint32_t bst = 0;
        for (int c = 255; c >= 0; --c) {
            cum += lh[c];
            if (cum >= (uint32_t)KSEL) { bst = (uint32_t)c; break; }
        }
        s_bst = bst;
    }
    __syncthreads();
    uint32_t bst = s_bst;
    int ibase = (blk & 63) * 4096;
    size_t fbase = ((size_t)b * (NN / 2)) + (size_t)(blk & 63) * 2048;
#pragma unroll
    for (int k = 0; k < 8; ++k) {
        float4 v = probs[fbase + k * 256 + t];
        int i0 = ibase + (k * 256 + t) * 2;
#pragma unroll
        for (int e = 0; e < 2; ++e) {
            float sc = e ? v.w : v.y;
            if (score_bin(sc) >= bst) {
                uint32_t p = atomicAdd(&lcnt, 1u);
                if (p < STAGE_CAP) {
                    uint32_t bits = __float_as_uint(sc);
                    stage[p] = ((uint64_t)bits << 32) | (uint32_t)(~(uint32_t)(i0 + e));
                }
            }
        }
    }
    __syncthreads();
    if (t == 0) {
        uint32_t m = lcnt > STAGE_CAP ? STAGE_CAP : lcnt;
        lbase = atomicAdd(&cnt[b], m);
        lcnt = m;
    }
    __syncthreads();
    uint32_t m = lcnt, base = lbase;
    for (uint32_t s = t; s < m; s += 256) {
        uint32_t pos = base + s;
        if (pos < CAND_CAP) cand[((uint64_t)b << 13) + pos] = stage[s];
    }
}

// ---------- K4a: bitonic phase A — sort each 1024-chunk DESCENDING (local dir) ----------
__launch_bounds__(512)
__global__ void k_sort1(const uint32_t* __restrict__ cnt, uint64_t* __restrict__ cand) {
    __shared__ uint64_t key[1024];
    int b = blockIdx.y, ch = blockIdx.x, t = threadIdx.x;
    uint32_t M = cnt[b]; if (M > CAND_CAP) M = CAND_CAP;
    uint64_t* cb = cand + ((uint64_t)b << 13);
    int base = ch << 10;
    for (int i = t; i < 1024; i += 512) key[i] = ((uint32_t)(base + i) < M) ? cb[base + i] : 0ull;
    __syncthreads();
    for (int kk = 2; kk <= 1024; kk <<= 1) {
        for (int j = kk >> 1; j > 0; j >>= 1) {
            for (int e = t; e < 1024; e += 512) {
                int ixj = e ^ j;
                if (ixj > e) {
                    uint64_t a = key[e], c = key[ixj];
                    bool ddd = ((e & kk) == 0);            // local direction: descending chunk
                    if ((a < c) == ddd) { key[e] = c; key[ixj] = a; }
                }
            }
            __syncthreads();
        }
    }
    for (int i = t; i < 1024; i += 512) cb[base + i] = key[i];
}

// ---------- K4b: fused merge levels 1024->2048->4096, in LDS, per 4096-segment ----------
// Merge-path binary searches (descending, unique keys except interchangeable zeros).
__launch_bounds__(512)
__global__ void k_merge2(const uint64_t* __restrict__ src, uint64_t* __restrict__ dst) {
    __shared__ uint64_t k1[4096];
    __shared__ uint64_t k2[4096];
    int b = blockIdx.y, seg = blockIdx.x, t = threadIdx.x;
    const uint64_t* base = src + ((uint64_t)b << 13) + (size_t)seg * 4096;
    for (int i = t; i < 4096; i += 512) k1[i] = base[i];
    __syncthreads();
    // level 1: merge 1024-run pairs -> two 2048 runs
    for (int o = t; o < 4096; o += 512) {
        int pair = o >> 11;
        int ko = o & 2047;
        const uint64_t* A = k1 + (pair << 11);
        const uint64_t* B = A + 1024;
        int lo = ko - 1024; if (lo < 0) lo = 0;
        int hi = ko < 1024 ? ko : 1024;
        while (lo < hi) {
            int m = (lo + hi) >> 1;
            int tt = ko - m - 1;
            uint64_t bv = (tt < 0) ? ~0ull : (tt >= 1024 ? 0ull : B[tt]);
            if (A[m] > bv) lo = m + 1; else hi = m;
        }
        int i = lo, j = ko - lo;
        uint64_t av = (i >= 1024) ? 0ull : A[i];
        uint64_t bv = (j >= 1024) ? 0ull : B[j];
        k2[o] = (av > bv) ? av : bv;
    }
    __syncthreads();
    // level 2: merge the two 2048 runs -> 4096, write out
    uint64_t* outp = dst + ((uint64_t)b << 13) + (size_t)seg * 4096;
    for (int o = t; o < 4096; o += 512) {
        const uint64_t* A = k2;
        const uint64_t* B = k2 + 2048;
        int lo = o - 2048; if (lo < 0) lo = 0;
        int hi = o < 2048 ? o : 2048;
        while (lo < hi) {
            int m = (lo + hi) >> 1;
            int tt = o - m - 1;
            uint64_t bv = (tt < 0) ? ~0ull : (tt >= 2048 ? 0ull : B[tt]);
            if (A[m] > bv) lo = m + 1; else hi = m;
        }
        int i = lo, j = o - lo;
        uint64_t av = (i >= 2048) ? 0ull : A[i];
        uint64_t bv = (j >= 2048) ? 0ull : B[j];
        outp[o] = (av > bv) ? av : bv;
    }
}

// ---------- K4c: final merge level (R=4096) fused with gather+decode ----------
__launch_bounds__(256)
__global__ void k_merge_decode(const uint64_t* __restrict__ src,
                               const float4* __restrict__ rpn_bbox, const float4* __restrict__ anchors,
                               float4* __restrict__ boxes, float* __restrict__ scoresS,
                               float* __restrict__ areas) {
    const int R = 4096;
    int b = blockIdx.y;
    int k = (blockIdx.x << 8) + threadIdx.x;        // [0, 6144)
    if (k >= KPAD2) return;
    const uint64_t* A = src + ((uint64_t)b << 13);
    const uint64_t* B = A + R;
    int lo = k - R; if (lo < 0) lo = 0;
    int hi = k < R ? k : R;
    while (lo < hi) {
        int m = (lo + hi) >> 1;
        int t = k - m - 1;
        uint64_t bv = (t < 0) ? ~0ull : (t >= R ? 0ull : B[t]);
        if (A[m] > bv) lo = m + 1; else hi = m;
    }
    int i = lo, j = k - lo;
    uint64_t av = (i >= R) ? 0ull : A[i];
    uint64_t bv = (j >= R) ? 0ull : B[j];
    uint64_t k64 = (av > bv) ? av : bv;

    float4 bx = make_float4(0.f, 0.f, 0.f, 0.f);
    float sc = 0.f, ar = 0.f;
    if (k < KSEL) {
        uint32_t idx = ~(uint32_t)(k64 & 0xFFFFFFFFull);
        sc = __uint_as_float((uint32_t)(k64 >> 32));
        size_t off = ((size_t)b << 18) + idx;
        float4 a = anchors[off];
        float4 d4 = rpn_bbox[off];
        float d0 = __fmul_rn(d4.x, 0.1f), d1 = __fmul_rn(d4.y, 0.1f);
        float d2 = __fmul_rn(d4.z, 0.2f), d3 = __fmul_rn(d4.w, 0.2f);
        float h = __fsub_rn(a.z, a.x), w = __fsub_rn(a.w, a.y);
        float cy = __fadd_rn(__fadd_rn(a.x, __fmul_rn(0.5f, h)), __fmul_rn(d0, h));
        float cx = __fadd_rn(__fadd_rn(a.y, __fmul_rn(0.5f, w)), __fmul_rn(d1, w));
        float h2 = __fmul_rn(h, expf(d2));
        float w2 = __fmul_rn(w, expf(d3));
        float y1 = __fsub_rn(cy, __fmul_rn(0.5f, h2));
        float x1 = __fsub_rn(cx, __fmul_rn(0.5f, w2));
        float y2 = __fadd_rn(cy, __fmul_rn(0.5f, h2));
        float x2 = __fadd_rn(cx, __fmul_rn(0.5f, w2));
        y1 = fminf(fmaxf(y1, 0.f), 1.f); x1 = fminf(fmaxf(x1, 0.f), 1.f);
        y2 = fminf(fmaxf(y2, 0.f), 1.f); x2 = fminf(fmaxf(x2, 0.f), 1.f);
        bx = make_float4(y1, x1, y2, x2);
        ar = __fmul_rn(__fsub_rn(y2, y1), __fsub_rn(x2, x1));
    }
    boxes[b * KPAD2 + k] = bx;
    scoresS[b * KPAD2 + k] = sc;
    areas[b * KPAD2 + k] = ar;
}

// ---------- K5: suppression bit rows, 1 row/thread, column-half split ----------
__launch_bounds__(256)
__global__ void k_matc(int w0, const float4* __restrict__ boxes, const float* __restrict__ areas,
                       uint64_t* __restrict__ mat, uint64_t* __restrict__ diag,
                       const uint32_t* __restrict__ done) {
    int b = blockIdx.y;
    if (done[b]) return;
    int q2 = blockIdx.x;
    int half = q2 & 1;
    int q = q2 >> 1, W = w0;
    while (q >= W + 1) { q -= W + 1; ++W; }
    int sub = q;                          // [0, W]
    int t = threadIdx.x;
    __shared__ float4 sb[128];
    __shared__ float sa[128];
    size_t bb = (size_t)b * KPAD2;
    int j0 = (W << 8) + (half << 7);      // 128 columns of word W
    if (t < 128) { sb[t] = boxes[bb + j0 + t]; sa[t] = areas[bb + j0 + t]; }
    __syncthreads();
    int i = (sub << 8) + t;               // this thread's row
    float4 bi = boxes[bb + i];
    float ai = areas[bb + i];
    uint32_t a0 = 0, a1 = 0, a2 = 0, a3 = 0;
#pragma unroll 4
    for (int jj = 0; jj < 32; ++jj) {
        a0 |= sup_bit(bi, ai, sb[jj], sa[jj]) << jj;
        a1 |= sup_bit(bi, ai, sb[32 + jj], sa[32 + jj]) << jj;
        a2 |= sup_bit(bi, ai, sb[64 + jj], sa[64 + jj]) << jj;
        a3 |= sup_bit(bi, ai, sb[96 + jj], sa[96 + jj]) << jj;
    }
    uint64_t* row;
    if (sub == W) {
        row = diag + (uint64_t)b * DIAG_U64_PB + (uint64_t)((W << 8) + t) * 4;
    } else {
        row = mat + (uint64_t)b * MAT_U64_PB + 512ull * W * (W - 1) + (uint64_t)i * 4;
    }
    ulonglong2 v;
    v.x = (uint64_t)a0 | ((uint64_t)a1 << 32);    // subword 2h
    v.y = (uint64_t)a2 | ((uint64_t)a3 << 32);    // subword 2h+1
    *(ulonglong2*)(row + (half << 1)) = v;
}

// ---------- K6: greedy NMS over words [w0,w1); bulk-pick (first-suppressor) ----------
__launch_bounds__(256)
__global__ void k_nms_chunk(int w0, int w1, int final_chunk,
                            const float4* __restrict__ boxes, const float* __restrict__ scoresS,
                            const uint64_t* __restrict__ diag, const uint64_t* __restrict__ mat,
                            uint32_t* __restrict__ gsel, uint32_t* __restrict__ ncount,
                            uint32_t* __restrict__ done, float* __restrict__ out) {
    __shared__ uint32_t sel[PROP];           // 4 KB (global indices)
    __shared__ uint64_t diagrow[256][4];     // 8 KB
    __shared__ uint32_t suppw[8];
    __shared__ uint32_t s_count;

    int b = blockIdx.x;
    if (done[b]) return;
    int tid = threadIdx.x;
    int wid = tid >> 6, lane = tid & 63;
    size_t bb = (size_t)b * KPAD2;
    const uint64_t* mb = mat + (uint64_t)b * MAT_U64_PB;
    const uint64_t* dgb = diag + (uint64_t)b * DIAG_U64_PB;
    uint32_t* gs = gsel + b * 1024;

    int count = (int)ncount[b];
    for (int r = tid; r < count; r += 256) sel[r] = gs[r];
    __syncthreads();

    for (int W = w0; W < w1; ++W) {
        // stage diag rows of word W into LDS; zero suppw
        {
            const ulonglong2* src = (const ulonglong2*)(dgb + (uint64_t)(W << 8) * 4);
            ulonglong2* dst = (ulonglong2*)&diagrow[0][0];
            dst[tid * 2] = src[tid * 2];
            dst[tid * 2 + 1] = src[tid * 2 + 1];
        }
        if (tid < 8) suppw[tid] = 0u;
        __syncthreads();
        // crossing gather: rows of prior selections vs word W (4 slots/thread)
        uint64_t acc0 = 0, acc1 = 0, acc2 = 0, acc3 = 0;
        {
            const uint64_t* col = mb + 512ull * W * (W - 1);
            uint32_t c = (uint32_t)count;
            uint32_t i0 = tid, i1 = tid + 256, i2 = tid + 512, i3 = tid + 768;
            if (i0 < c) { const ulonglong2* r = (const ulonglong2*)(col + 4u * sel[i0]);
                          ulonglong2 x = r[0], y = r[1];
                          acc0 |= x.x; acc1 |= x.y; acc2 |= y.x; acc3 |= y.y; }
            if (i1 < c) { const ulonglong2* r = (const ulonglong2*)(col + 4u * sel[i1]);
                          ulonglong2 x = r[0], y = r[1];
                          acc0 |= x.x; acc1 |= x.y; acc2 |= y.x; acc3 |= y.y; }
            if (i2 < c) { const ulonglong2* r = (const ulonglong2*)(col + 4u * sel[i2]);
                          ulonglong2 x = r[0], y = r[1];
                          acc0 |= x.x; acc1 |= x.y; acc2 |= y.x; acc3 |= y.y; }
            if (i3 < c) { const ulonglong2* r = (const ulonglong2*)(col + 4u * sel[i3]);
                          ulonglong2 x = r[0], y = r[1];
                          acc0 |= x.x; acc1 |= x.y; acc2 |= y.x; acc3 |= y.y; }
        }
#pragma unroll
        for (int off = 32; off; off >>= 1) {
            acc0 |= shfl_xor_u64(acc0, off);
            acc1 |= shfl_xor_u64(acc1, off);
            acc2 |= shfl_xor_u64(acc2, off);
            acc3 |= shfl_xor_u64(acc3, off);
        }
        if (lane == 0) {
            if (acc0) { atomicOr(&suppw[0], (uint32_t)acc0); atomicOr(&suppw[1], (uint32_t)(acc0 >> 32)); }
            if (acc1) { atomicOr(&suppw[2], (uint32_t)acc1); atomicOr(&suppw[3], (uint32_t)(acc1 >> 32)); }
            if (acc2) { atomicOr(&suppw[4], (uint32_t)acc2); atomicOr(&suppw[5], (uint32_t)(acc2 >> 32)); }
            if (acc3) { atomicOr(&suppw[6], (uint32_t)acc3); atomicOr(&suppw[7], (uint32_t)(acc3 >> 32)); }
        }
        __syncthreads();
        int count_old = count;
        // wave 0: bulk greedy selection (first-suppressor batching; proven r12)
        if (wid == 0) {
            uint64_t a0 = ~(((uint64_t)suppw[1] << 32) | suppw[0]);
            uint64_t a1 = ~(((uint64_t)suppw[3] << 32) | suppw[2]);
            uint64_t a2 = ~(((uint64_t)suppw[5] << 32) | suppw[4]);
            uint64_t a3 = ~(((uint64_t)suppw[7] << 32) | suppw[6]);
            if (W == NW2 - 1) { a1 &= (1ull << 48) - 1; a2 = 0; a3 = 0; }   // j < 6000 valid
            uint64_t pk0 = 0, pk1 = 0, pk2 = 0, pk3 = 0;
            uint64_t hi_mask = (lane == 63) ? 0ull : (~0ull << (lane + 1));

#define SUBP(S, AS, PK)                                                       \
            if (AS && count < PROP) {                                         \
                uint64_t own = diagrow[(S << 6) + lane][S];                   \
                while (AS && count < PROP) {                                  \
                    uint32_t alive_l = (uint32_t)((AS >> lane) & 1ull);       \
                    uint64_t inter = own & AS & hi_mask;                      \
                    unsigned long long conf = __ballot(alive_l && (inter != 0ull)); \
                    uint64_t run, rowc = 0ull;                                \
                    if (conf == 0ull) { run = AS; }                           \
                    else {                                                    \
                        uint32_t c = (uint32_t)__builtin_ctzll(conf);         \
                        uint64_t lo = ((1ull << c) << 1) - 1ull;              \
                        run = AS & lo;                                        \
                        rowc = rdlane64(own, c);                              \
                    }                                                         \
                    int pr = (int)__popcll(run);                              \
                    if (count + pr > PROP) {                                  \
                        int need = PROP - count;                              \
                        while (need-- > 0) {                                  \
                            uint32_t bp = (uint32_t)__builtin_ctzll(run);     \
                            PK |= 1ull << bp;                                 \
                            run &= run - 1ull;                                \
                        }                                                     \
                        count = PROP; AS = 0ull;                              \
                    } else {                                                  \
                        PK |= run; count += pr;                               \
                        AS &= ~run; AS &= ~rowc;                              \
                    }                                                         \
                }                                                             \
            }
            SUBP(0, a0, pk0)
            // transition: picked subword-0 boxes suppress subwords 1..3
            if (pk0 && count < PROP) {
                uint32_t pl = (uint32_t)((pk0 >> lane) & 1ull);
                uint64_t x1 = pl ? diagrow[lane][1] : 0ull;
                uint64_t x2 = pl ? diagrow[lane][2] : 0ull;
                uint64_t x3 = pl ? diagrow[lane][3] : 0ull;
#pragma unroll
                for (int off = 32; off; off >>= 1) {
                    x1 |= shfl_xor_u64(x1, off);
                    x2 |= shfl_xor_u64(x2, off);
                    x3 |= shfl_xor_u64(x3, off);
                }
                a1 &= ~rdfl64(x1); a2 &= ~rdfl64(x2); a3 &= ~rdfl64(x3);
            }
            SUBP(1, a1, pk1)
            if (pk1 && count < PROP) {
                uint32_t pl = (uint32_t)((pk1 >> lane) & 1ull);
                uint64_t x2 = pl ? diagrow[64 + lane][2] : 0ull;
                uint64_t x3 = pl ? diagrow[64 + lane][3] : 0ull;
#pragma unroll
                for (int off = 32; off; off >>= 1) {
                    x2 |= shfl_xor_u64(x2, off);
                    x3 |= shfl_xor_u64(x3, off);
                }
                a2 &= ~rdfl64(x2); a3 &= ~rdfl64(x3);
            }
            SUBP(2, a2, pk2)
            if (pk2 && count < PROP) {
                uint32_t pl = (uint32_t)((pk2 >> lane) & 1ull);
                uint64_t x3 = pl ? diagrow[128 + lane][3] : 0ull;
#pragma unroll
                for (int off = 32; off; off >>= 1) x3 |= shfl_xor_u64(x3, off);
                a3 &= ~rdfl64(x3);
            }
            SUBP(3, a3, pk3)
#undef SUBP
            // parallel append: picks were made in ascending (S, bp) order
            uint32_t nb = (uint32_t)count_old;
#define APPEND(S, PK) {                                                       \
            if (PK) {                                                         \
                uint32_t my = (uint32_t)((PK >> lane) & 1ull);                \
                uint32_t rank = (uint32_t)__popcll(PK & ((1ull << lane) - 1ull));\
                if (my) {                                                     \
                    uint32_t v = (uint32_t)((W << 8) + (S << 6) + lane);      \
                    sel[nb + rank] = v;                                       \
                    gs[nb + rank] = v;                                        \
                }                                                             \
                nb += (uint32_t)__popcll(PK);                                 \
            } }
            APPEND(0, pk0)
            APPEND(1, pk1)
            APPEND(2, pk2)
            APPEND(3, pk3)
#undef APPEND
            if (lane == 0) s_count = (uint32_t)count;
        }
        __syncthreads();
        count = (int)s_count;
        if (count >= PROP) break;
    }

    if (count >= PROP || final_chunk) {
        if (tid == 0) { done[b] = 1u; ncount[b] = (uint32_t)count; }
        float* prop = out + b * (PROP * 4);
        float* psc = out + BB * PROP * 4 + b * PROP;
        for (int r = tid; r < PROP; r += 256) {
            if (r < count) {
                uint32_t j = sel[r];
                float4 bx = boxes[bb + j];
                *(float4*)(prop + r * 4) = bx;
                psc[r] = scoresS[bb + j];
            } else {
                *(float4*)(prop + r * 4) = make_float4(0.f, 0.f, 0.f, 0.f);
                psc[r] = 0.f;
            }
        }
    } else {
        if (tid == 0) ncount[b] = (uint32_t)count;
    }
}

extern "C" void kernel_launch(void* const* d_in, const int* in_sizes, int n_in,
                              void* d_out, int out_size, void* d_ws, size_t ws_size,
                              hipStream_t stream) {
    const float4* probs = (const float4*)d_in[0];
    const float4* rpn_bbox = (const float4*)d_in[1];
    const float4* anchors = (const float4*)d_in[2];
    float* out = (float*)d_out;

    uint8_t* p = (uint8_t*)d_ws;
    size_t off = 0;
    auto alloc = [&](size_t bytes) -> void* {
        void* q = p + off;
        off += (bytes + 255) & ~(size_t)255;
        return q;
    };
    uint32_t* bhist = (uint32_t*)alloc((size_t)BB * 64 * 256 * 4);         // 512 KB
    uint32_t* cnt = (uint32_t*)alloc(BB * 4);
    uint32_t* ncount = (uint32_t*)alloc(BB * 4);
    uint32_t* ndone = (uint32_t*)alloc(BB * 4);
    uint64_t* cand = (uint64_t*)alloc((size_t)BB * CAND_CAP * 8);          // 512 KB
    uint64_t* cand2 = (uint64_t*)alloc((size_t)BB * CAND_CAP * 8);         // 512 KB
    float4* boxes = (float4*)alloc((size_t)BB * KPAD2 * 16);               // 768 KB
    float* scoresS = (float*)alloc((size_t)BB * KPAD2 * 4);
    float* areas = (float*)alloc((size_t)BB * KPAD2 * 4);
    uint32_t* gsel = (uint32_t*)alloc((size_t)BB * 1024 * 4);              // 32 KB
    uint64_t* diag = (uint64_t*)alloc((size_t)BB * DIAG_U64_PB * 8);       // 1.57 MB
    uint64_t* mat = (uint64_t*)alloc((size_t)BB * MAT_U64_PB * 8);         // 18.1 MB

    if (off > ws_size) {
        hipMemsetAsync(d_out, 0, (size_t)out_size * 4, stream);
        return;
    }

    k_hist<<<BB * BPB, 256, 0, stream>>>(probs, bhist, cnt, ncount, ndone);
    k_compact<<<BB * BPB, 256, 0, stream>>>(probs, bhist, cnt, cand);
    dim3 gs1(8, BB);
    k_sort1<<<gs1, 512, 0, stream>>>(cnt, cand);
    dim3 gm2(2, BB);
    k_merge2<<<gm2, 512, 0, stream>>>(cand, cand2);
    dim3 gmd(24, BB);   // 24*256 = 6144 ranks materialized
    k_merge_decode<<<gmd, 256, 0, stream>>>(cand2, rpn_bbox, anchors, boxes, scoresS, areas);

    const int cb[3] = {0, 6, 24};
    for (int c = 0; c < 2; ++c) {
        int w0 = cb[c], w1 = cb[c + 1];
        int nblk = 0;
        for (int W = w0; W < w1; ++W) nblk += W + 1;
        dim3 gm(nblk * 2, BB);   // x2: column-half split
        k_matc<<<gm, 256, 0, stream>>>(w0, boxes, areas, mat, diag, ndone);
        k_nms_chunk<<<BB, 256, 0, stream>>>(w0, w1, (w1 == NW2) ? 1 : 0,
                                            boxes, scoresS, diag, mat,
                                            gsel, ncount, ndone, out);
    }
}

// Round 17
// 101.727 us; speedup vs baseline: 1.0933x; 1.0933x over previous
//
#include <hip/hip_runtime.h>
#include <stdint.h>

#define BB 8
#define NN 262144
#define KSEL 6000
#define KPAD2 6144
#define NW2 24               // 24 words of 256 boxes
#define PROP 1000
#define NMS_THR 0.7f
#define CAND_CAP 8192
#define BPB 64               // blocks per batch for hist/compact (4096 items each)
#define STAGE_CAP 768
#define MAT_U64_PB 282624ull // sum_{W=1..23} 256*W rows * 4 u64 = 512*23*24
#define DIAG_U64_PB 24576ull // 24*256*4

// ---------- helpers ----------
__device__ __forceinline__ unsigned long long shfl_xor_u64(unsigned long long v, int m) {
    unsigned lo = (unsigned)v, hi = (unsigned)(v >> 32);
    lo = __shfl_xor(lo, m);
    hi = __shfl_xor(hi, m);
    return ((unsigned long long)hi << 32) | lo;
}
__device__ __forceinline__ uint64_t rdfl64(uint64_t v) {
    uint32_t lo = __builtin_amdgcn_readfirstlane((uint32_t)v);
    uint32_t hi = __builtin_amdgcn_readfirstlane((uint32_t)(v >> 32));
    return ((uint64_t)hi << 32) | lo;
}
__device__ __forceinline__ uint64_t rdlane64(uint64_t v, uint32_t l) {
    uint32_t lo = __builtin_amdgcn_readlane((uint32_t)v, l);
    uint32_t hi = __builtin_amdgcn_readlane((uint32_t)(v >> 32), l);
    return ((uint64_t)hi << 32) | lo;
}

// Exact replacement for RN(inter/den) > 0.7f (den > 0 always):
//   RN(q) > c  <=>  q >= M, M = c + 2^-25 (midpoint; tie rounds to even = c_next > c).
//   M has 25-bit significand, den 24 bits -> M*den exact in f64; comparison exact.
__device__ __forceinline__ uint32_t sup_bit(const float4 bi, float ai, const float4 bj, float aj) {
    float y1 = fmaxf(bi.x, bj.x), x1 = fmaxf(bi.y, bj.y);
    float y2 = fminf(bi.z, bj.z), x2 = fminf(bi.w, bj.w);
    float inter = __fmul_rn(fmaxf(__fsub_rn(y2, y1), 0.f), fmaxf(__fsub_rn(x2, x1), 0.f));
    float den = __fadd_rn(__fsub_rn(__fadd_rn(ai, aj), inter), 1e-10f);
    const double MSUP = 23488103.0 / 33554432.0;   // 0.7f + 2^-25, exact
    return (double)inter >= MSUP * (double)den;
}

__device__ __forceinline__ uint32_t score_bin(float sc) {
    uint32_t u = (uint32_t)(sc * 16777216.0f);
    u = u > 16777215u ? 16777215u : u;
    return u >> 16;
}

// ---------- K0: zero the small state ----------
__global__ void k_zero(uint32_t* __restrict__ ghist, uint32_t* __restrict__ cnt,
                       uint32_t* __restrict__ ncount, uint32_t* __restrict__ ndone) {
    int b = blockIdx.x, t = threadIdx.x;
    ghist[(b << 8) + t] = 0u;
    if (t == 0) { cnt[b] = 0u; ncount[b] = 0u; ndone[b] = 0u; }
}

// ---------- K1: per-block LDS histogram -> global 256-bin per-batch hist ----------
__global__ void k_hist(const float4* __restrict__ probs, uint32_t* __restrict__ ghist) {
    __shared__ uint32_t lh[256];
    int blk = blockIdx.x;
    int b = blk >> 6;
    int t = threadIdx.x;
    lh[t] = 0u;
    __syncthreads();
    size_t fbase = ((size_t)b * (NN / 2)) + (size_t)(blk & 63) * 2048;
#pragma unroll
    for (int k = 0; k < 8; ++k) {
        float4 v = probs[fbase + k * 256 + t];
        atomicAdd(&lh[score_bin(v.y)], 1u);
        atomicAdd(&lh[score_bin(v.w)], 1u);
    }
    __syncthreads();
    uint32_t c = lh[t];
    if (c) atomicAdd(&ghist[(b << 8) + t], c);
}

// ---------- K3: compact candidates (threshold derived in-block), block-aggregated ----------
__global__ void k_compact(const float4* __restrict__ probs, const uint32_t* __restrict__ ghist,
                          uint32_t* __restrict__ cnt, uint64_t* __restrict__ cand) {
    __shared__ uint64_t stage[STAGE_CAP];
    __shared__ uint32_t lh[256];
    __shared__ uint32_t s_bst, lcnt, lbase;
    int blk = blockIdx.x;
    int b = blk >> 6;
    int t = threadIdx.x;
    lh[t] = ghist[(b << 8) + t];
    if (t == 0) lcnt = 0u;
    __syncthreads();
    if (t == 0) {
        uint32_t cum = 0; uint32_t bst = 0;
        for (int c = 255; c >= 0; --c) {
            cum += lh[c];
            if (cum >= (uint32_t)KSEL) { bst = (uint32_t)c; break; }
        }
        s_bst = bst;
    }
    __syncthreads();
    uint32_t bst = s_bst;
    int ibase = (blk & 63) * 4096;
    size_t fbase = ((size_t)b * (NN / 2)) + (size_t)(blk & 63) * 2048;
#pragma unroll
    for (int k = 0; k < 8; ++k) {
        float4 v = probs[fbase + k * 256 + t];
        int i0 = ibase + (k * 256 + t) * 2;
#pragma unroll
        for (int e = 0; e < 2; ++e) {
            float sc = e ? v.w : v.y;
            if (score_bin(sc) >= bst) {
                uint32_t p = atomicAdd(&lcnt, 1u);
                if (p < STAGE_CAP) {
                    uint32_t bits = __float_as_uint(sc);
                    stage[p] = ((uint64_t)bits << 32) | (uint32_t)(~(uint32_t)(i0 + e));
                }
            }
        }
    }
    __syncthreads();
    if (t == 0) {
        uint32_t m = lcnt > STAGE_CAP ? STAGE_CAP : lcnt;
        lbase = atomicAdd(&cnt[b], m);
        lcnt = m;
    }
    __syncthreads();
    uint32_t m = lcnt, base = lbase;
    for (uint32_t s = t; s < m; s += 256) {
        uint32_t pos = base + s;
        if (pos < CAND_CAP) cand[((uint64_t)b << 13) + pos] = stage[s];
    }
}

// ---------- K4a: bitonic phase A — sort each 1024-chunk DESCENDING (local dir) ----------
__launch_bounds__(512)
__global__ void k_sort1(const uint32_t* __restrict__ cnt, uint64_t* __restrict__ cand) {
    __shared__ uint64_t key[1024];
    int b = blockIdx.y, ch = blockIdx.x, t = threadIdx.x;
    uint32_t M = cnt[b]; if (M > CAND_CAP) M = CAND_CAP;
    uint64_t* cb = cand + ((uint64_t)b << 13);
    int base = ch << 10;
    for (int i = t; i < 1024; i += 512) key[i] = ((uint32_t)(base + i) < M) ? cb[base + i] : 0ull;
    __syncthreads();
    for (int kk = 2; kk <= 1024; kk <<= 1) {
        for (int j = kk >> 1; j > 0; j >>= 1) {
            for (int e = t; e < 1024; e += 512) {
                int ixj = e ^ j;
                if (ixj > e) {
                    uint64_t a = key[e], c = key[ixj];
                    bool ddd = ((e & kk) == 0);            // local direction: descending chunk
                    if ((a < c) == ddd) { key[e] = c; key[ixj] = a; }
                }
            }
            __syncthreads();
        }
    }
    for (int i = t; i < 1024; i += 512) cb[base + i] = key[i];
}

// ---------- K4b: merge-path level — merge descending runs of length R into 2R ----------
__launch_bounds__(256)
__global__ void k_merge(int R, const uint64_t* __restrict__ src, uint64_t* __restrict__ dst) {
    int b = blockIdx.y;
    int k = (blockIdx.x << 8) + threadIdx.x;        // [0, 8192)
    const uint64_t* base = src + ((uint64_t)b << 13);
    int run = k / (2 * R);
    int ko = k - run * (2 * R);                     // rank within merged run
    const uint64_t* A = base + (size_t)run * 2 * R;
    const uint64_t* B = A + R;
    int lo = ko - R; if (lo < 0) lo = 0;
    int hi = ko < R ? ko : R;
    while (lo < hi) {
        int m = (lo + hi) >> 1;
        int t = ko - m - 1;
        uint64_t bv = (t < 0) ? ~0ull : (t >= R ? 0ull : B[t]);
        if (A[m] > bv) lo = m + 1; else hi = m;     // A[m] comes before rank ko
    }
    int i = lo, j = ko - lo;
    uint64_t av = (i >= R) ? 0ull : A[i];
    uint64_t bv = (j >= R) ? 0ull : B[j];
    dst[((uint64_t)b << 13) + k] = (av > bv) ? av : bv;
}

// ---------- K4c: final merge level (R=4096) fused with gather+decode ----------
__launch_bounds__(256)
__global__ void k_merge_decode(const uint64_t* __restrict__ src,
                               const float4* __restrict__ rpn_bbox, const float4* __restrict__ anchors,
                               float4* __restrict__ boxes, float* __restrict__ scoresS,
                               float* __restrict__ areas) {
    const int R = 4096;
    int b = blockIdx.y;
    int k = (blockIdx.x << 8) + threadIdx.x;        // [0, 6144)
    if (k >= KPAD2) return;
    const uint64_t* A = src + ((uint64_t)b << 13);
    const uint64_t* B = A + R;
    int lo = k - R; if (lo < 0) lo = 0;
    int hi = k < R ? k : R;
    while (lo < hi) {
        int m = (lo + hi) >> 1;
        int t = k - m - 1;
        uint64_t bv = (t < 0) ? ~0ull : (t >= R ? 0ull : B[t]);
        if (A[m] > bv) lo = m + 1; else hi = m;
    }
    int i = lo, j = k - lo;
    uint64_t av = (i >= R) ? 0ull : A[i];
    uint64_t bv = (j >= R) ? 0ull : B[j];
    uint64_t k64 = (av > bv) ? av : bv;

    float4 bx = make_float4(0.f, 0.f, 0.f, 0.f);
    float sc = 0.f, ar = 0.f;
    if (k < KSEL) {
        uint32_t idx = ~(uint32_t)(k64 & 0xFFFFFFFFull);
        sc = __uint_as_float((uint32_t)(k64 >> 32));
        size_t off = ((size_t)b << 18) + idx;
        float4 a = anchors[off];
        float4 d4 = rpn_bbox[off];
        float d0 = __fmul_rn(d4.x, 0.1f), d1 = __fmul_rn(d4.y, 0.1f);
        float d2 = __fmul_rn(d4.z, 0.2f), d3 = __fmul_rn(d4.w, 0.2f);
        float h = __fsub_rn(a.z, a.x), w = __fsub_rn(a.w, a.y);
        float cy = __fadd_rn(__fadd_rn(a.x, __fmul_rn(0.5f, h)), __fmul_rn(d0, h));
        float cx = __fadd_rn(__fadd_rn(a.y, __fmul_rn(0.5f, w)), __fmul_rn(d1, w));
        float h2 = __fmul_rn(h, expf(d2));
        float w2 = __fmul_rn(w, expf(d3));
        float y1 = __fsub_rn(cy, __fmul_rn(0.5f, h2));
        float x1 = __fsub_rn(cx, __fmul_rn(0.5f, w2));
        float y2 = __fadd_rn(cy, __fmul_rn(0.5f, h2));
        float x2 = __fadd_rn(cx, __fmul_rn(0.5f, w2));
        y1 = fminf(fmaxf(y1, 0.f), 1.f); x1 = fminf(fmaxf(x1, 0.f), 1.f);
        y2 = fminf(fmaxf(y2, 0.f), 1.f); x2 = fminf(fmaxf(x2, 0.f), 1.f);
        bx = make_float4(y1, x1, y2, x2);
        ar = __fmul_rn(__fsub_rn(y2, y1), __fsub_rn(x2, x1));
    }
    boxes[b * KPAD2 + k] = bx;
    scoresS[b * KPAD2 + k] = sc;
    areas[b * KPAD2 + k] = ar;
}

// ---------- K5: suppression bit rows, 1 row/thread, column-half split ----------
__launch_bounds__(256)
__global__ void k_matc(int w0, const float4* __restrict__ boxes, const float* __restrict__ areas,
                       uint64_t* __restrict__ mat, uint64_t* __restrict__ diag,
                       const uint32_t* __restrict__ done) {
    int b = blockIdx.y;
    if (done[b]) return;
    int q2 = blockIdx.x;
    int half = q2 & 1;
    int q = q2 >> 1, W = w0;
    while (q >= W + 1) { q -= W + 1; ++W; }
    int sub = q;                          // [0, W]
    int t = threadIdx.x;
    __shared__ float4 sb[128];
    __shared__ float sa[128];
    size_t bb = (size_t)b * KPAD2;
    int j0 = (W << 8) + (half << 7);      // 128 columns of word W
    if (t < 128) { sb[t] = boxes[bb + j0 + t]; sa[t] = areas[bb + j0 + t]; }
    __syncthreads();
    int i = (sub << 8) + t;               // this thread's row
    float4 bi = boxes[bb + i];
    float ai = areas[bb + i];
    uint32_t a0 = 0, a1 = 0, a2 = 0, a3 = 0;
#pragma unroll 4
    for (int jj = 0; jj < 32; ++jj) {
        a0 |= sup_bit(bi, ai, sb[jj], sa[jj]) << jj;
        a1 |= sup_bit(bi, ai, sb[32 + jj], sa[32 + jj]) << jj;
        a2 |= sup_bit(bi, ai, sb[64 + jj], sa[64 + jj]) << jj;
        a3 |= sup_bit(bi, ai, sb[96 + jj], sa[96 + jj]) << jj;
    }
    uint64_t* row;
    if (sub == W) {
        row = diag + (uint64_t)b * DIAG_U64_PB + (uint64_t)((W << 8) + t) * 4;
    } else {
        row = mat + (uint64_t)b * MAT_U64_PB + 512ull * W * (W - 1) + (uint64_t)i * 4;
    }
    ulonglong2 v;
    v.x = (uint64_t)a0 | ((uint64_t)a1 << 32);    // subword 2h
    v.y = (uint64_t)a2 | ((uint64_t)a3 << 32);    // subword 2h+1
    *(ulonglong2*)(row + (half << 1)) = v;
}

// ---------- K6: greedy NMS over words [w0,w1); bulk-pick (first-suppressor) ----------
__launch_bounds__(256)
__global__ void k_nms_chunk(int w0, int w1, int final_chunk,
                            const float4* __restrict__ boxes, const float* __restrict__ scoresS,
                            const uint64_t* __restrict__ diag, const uint64_t* __restrict__ mat,
                            uint32_t* __restrict__ gsel, uint32_t* __restrict__ ncount,
                            uint32_t* __restrict__ done, float* __restrict__ out) {
    __shared__ uint32_t sel[PROP];           // 4 KB (global indices)
    __shared__ uint64_t diagrow[256][4];     // 8 KB
    __shared__ uint32_t suppw[8];
    __shared__ uint32_t s_count;

    int b = blockIdx.x;
    if (done[b]) return;
    int tid = threadIdx.x;
    int wid = tid >> 6, lane = tid & 63;
    size_t bb = (size_t)b * KPAD2;
    const uint64_t* mb = mat + (uint64_t)b * MAT_U64_PB;
    const uint64_t* dgb = diag + (uint64_t)b * DIAG_U64_PB;
    uint32_t* gs = gsel + b * 1024;

    int count = (int)ncount[b];
    for (int r = tid; r < count; r += 256) sel[r] = gs[r];
    __syncthreads();

    for (int W = w0; W < w1; ++W) {
        // stage diag rows of word W into LDS; zero suppw
        {
            const ulonglong2* src = (const ulonglong2*)(dgb + (uint64_t)(W << 8) * 4);
            ulonglong2* dst = (ulonglong2*)&diagrow[0][0];
            dst[tid * 2] = src[tid * 2];
            dst[tid * 2 + 1] = src[tid * 2 + 1];
        }
        if (tid < 8) suppw[tid] = 0u;
        __syncthreads();
        // crossing gather: rows of prior selections vs word W (4 slots/thread)
        uint64_t acc0 = 0, acc1 = 0, acc2 = 0, acc3 = 0;
        {
            const uint64_t* col = mb + 512ull * W * (W - 1);
            uint32_t c = (uint32_t)count;
            uint32_t i0 = tid, i1 = tid + 256, i2 = tid + 512, i3 = tid + 768;
            if (i0 < c) { const ulonglong2* r = (const ulonglong2*)(col + 4u * sel[i0]);
                          ulonglong2 x = r[0], y = r[1];
                          acc0 |= x.x; acc1 |= x.y; acc2 |= y.x; acc3 |= y.y; }
            if (i1 < c) { const ulonglong2* r = (const ulonglong2*)(col + 4u * sel[i1]);
                          ulonglong2 x = r[0], y = r[1];
                          acc0 |= x.x; acc1 |= x.y; acc2 |= y.x; acc3 |= y.y; }
            if (i2 < c) { const ulonglong2* r = (const ulonglong2*)(col + 4u * sel[i2]);
                          ulonglong2 x = r[0], y = r[1];
                          acc0 |= x.x; acc1 |= x.y; acc2 |= y.x; acc3 |= y.y; }
            if (i3 < c) { const ulonglong2* r = (const ulonglong2*)(col + 4u * sel[i3]);
                          ulonglong2 x = r[0], y = r[1];
                          acc0 |= x.x; acc1 |= x.y; acc2 |= y.x; acc3 |= y.y; }
        }
#pragma unroll
        for (int off = 32; off; off >>= 1) {
            acc0 |= shfl_xor_u64(acc0, off);
            acc1 |= shfl_xor_u64(acc1, off);
            acc2 |= shfl_xor_u64(acc2, off);
            acc3 |= shfl_xor_u64(acc3, off);
        }
        if (lane == 0) {
            if (acc0) { atomicOr(&suppw[0], (uint32_t)acc0); atomicOr(&suppw[1], (uint32_t)(acc0 >> 32)); }
            if (acc1) { atomicOr(&suppw[2], (uint32_t)acc1); atomicOr(&suppw[3], (uint32_t)(acc1 >> 32)); }
            if (acc2) { atomicOr(&suppw[4], (uint32_t)acc2); atomicOr(&suppw[5], (uint32_t)(acc2 >> 32)); }
            if (acc3) { atomicOr(&suppw[6], (uint32_t)acc3); atomicOr(&suppw[7], (uint32_t)(acc3 >> 32)); }
        }
        __syncthreads();
        int count_old = count;
        // wave 0: bulk greedy selection (first-suppressor batching; proven r12)
        if (wid == 0) {
            uint64_t a0 = ~(((uint64_t)suppw[1] << 32) | suppw[0]);
            uint64_t a1 = ~(((uint64_t)suppw[3] << 32) | suppw[2]);
            uint64_t a2 = ~(((uint64_t)suppw[5] << 32) | suppw[4]);
            uint64_t a3 = ~(((uint64_t)suppw[7] << 32) | suppw[6]);
            if (W == NW2 - 1) { a1 &= (1ull << 48) - 1; a2 = 0; a3 = 0; }   // j < 6000 valid
            uint64_t pk0 = 0, pk1 = 0, pk2 = 0, pk3 = 0;
            uint64_t hi_mask = (lane == 63) ? 0ull : (~0ull << (lane + 1));

#define SUBP(S, AS, PK)                                                       \
            if (AS && count < PROP) {                                         \
                uint64_t own = diagrow[(S << 6) + lane][S];                   \
                while (AS && count < PROP) {                                  \
                    uint32_t alive_l = (uint32_t)((AS >> lane) & 1ull);       \
                    uint64_t inter = own & AS & hi_mask;                      \
                    unsigned long long conf = __ballot(alive_l && (inter != 0ull)); \
                    uint64_t run, rowc = 0ull;                                \
                    if (conf == 0ull) { run = AS; }                           \
                    else {                                                    \
                        uint32_t c = (uint32_t)__builtin_ctzll(conf);         \
                        uint64_t lo = ((1ull << c) << 1) - 1ull;              \
                        run = AS & lo;                                        \
                        rowc = rdlane64(own, c);                              \
                    }                                                         \
                    int pr = (int)__popcll(run);                              \
                    if (count + pr > PROP) {                                  \
                        int need = PROP - count;                              \
                        while (need-- > 0) {                                  \
                            uint32_t bp = (uint32_t)__builtin_ctzll(run);     \
                            PK |= 1ull << bp;                                 \
                            run &= run - 1ull;                                \
                        }                                                     \
                        count = PROP; AS = 0ull;                              \
                    } else {                                                  \
                        PK |= run; count += pr;                               \
                        AS &= ~run; AS &= ~rowc;                              \
                    }                                                         \
                }                                                             \
            }
            SUBP(0, a0, pk0)
            // transition: picked subword-0 boxes suppress subwords 1..3
            if (pk0 && count < PROP) {
                uint32_t pl = (uint32_t)((pk0 >> lane) & 1ull);
                uint64_t x1 = pl ? diagrow[lane][1] : 0ull;
                uint64_t x2 = pl ? diagrow[lane][2] : 0ull;
                uint64_t x3 = pl ? diagrow[lane][3] : 0ull;
#pragma unroll
                for (int off = 32; off; off >>= 1) {
                    x1 |= shfl_xor_u64(x1, off);
                    x2 |= shfl_xor_u64(x2, off);
                    x3 |= shfl_xor_u64(x3, off);
                }
                a1 &= ~rdfl64(x1); a2 &= ~rdfl64(x2); a3 &= ~rdfl64(x3);
            }
            SUBP(1, a1, pk1)
            if (pk1 && count < PROP) {
                uint32_t pl = (uint32_t)((pk1 >> lane) & 1ull);
                uint64_t x2 = pl ? diagrow[64 + lane][2] : 0ull;
                uint64_t x3 = pl ? diagrow[64 + lane][3] : 0ull;
#pragma unroll
                for (int off = 32; off; off >>= 1) {
                    x2 |= shfl_xor_u64(x2, off);
                    x3 |= shfl_xor_u64(x3, off);
                }
                a2 &= ~rdfl64(x2); a3 &= ~rdfl64(x3);
            }
            SUBP(2, a2, pk2)
            if (pk2 && count < PROP) {
                uint32_t pl = (uint32_t)((pk2 >> lane) & 1ull);
                uint64_t x3 = pl ? diagrow[128 + lane][3] : 0ull;
#pragma unroll
                for (int off = 32; off; off >>= 1) x3 |= shfl_xor_u64(x3, off);
                a3 &= ~rdfl64(x3);
            }
            SUBP(3, a3, pk3)
#undef SUBP
            // parallel append: picks were made in ascending (S, bp) order
            uint32_t nb = (uint32_t)count_old;
#define APPEND(S, PK) {                                                       \
            if (PK) {                                                         \
                uint32_t my = (uint32_t)((PK >> lane) & 1ull);                \
                uint32_t rank = (uint32_t)__popcll(PK & ((1ull << lane) - 1ull));\
                if (my) {                                                     \
                    uint32_t v = (uint32_t)((W << 8) + (S << 6) + lane);      \
                    sel[nb + rank] = v;                                       \
                    gs[nb + rank] = v;                                        \
                }                                                             \
                nb += (uint32_t)__popcll(PK);                                 \
            } }
            APPEND(0, pk0)
            APPEND(1, pk1)
            APPEND(2, pk2)
            APPEND(3, pk3)
#undef APPEND
            if (lane == 0) s_count = (uint32_t)count;
        }
        __syncthreads();
        count = (int)s_count;
        if (count >= PROP) break;
    }

    if (count >= PROP || final_chunk) {
        if (tid == 0) { done[b] = 1u; ncount[b] = (uint32_t)count; }
        float* prop = out + b * (PROP * 4);
        float* psc = out + BB * PROP * 4 + b * PROP;
        for (int r = tid; r < PROP; r += 256) {
            if (r < count) {
                uint32_t j = sel[r];
                float4 bx = boxes[bb + j];
                *(float4*)(prop + r * 4) = bx;
                psc[r] = scoresS[bb + j];
            } else {
                *(float4*)(prop + r * 4) = make_float4(0.f, 0.f, 0.f, 0.f);
                psc[r] = 0.f;
            }
        }
    } else {
        if (tid == 0) ncount[b] = (uint32_t)count;
    }
}

extern "C" void kernel_launch(void* const* d_in, const int* in_sizes, int n_in,
                              void* d_out, int out_size, void* d_ws, size_t ws_size,
                              hipStream_t stream) {
    const float4* probs = (const float4*)d_in[0];
    const float4* rpn_bbox = (const float4*)d_in[1];
    const float4* anchors = (const float4*)d_in[2];
    float* out = (float*)d_out;

    uint8_t* p = (uint8_t*)d_ws;
    size_t off = 0;
    auto alloc = [&](size_t bytes) -> void* {
        void* q = p + off;
        off += (bytes + 255) & ~(size_t)255;
        return q;
    };
    uint32_t* ghist = (uint32_t*)alloc((size_t)BB * 256 * 4);              // 8 KB
    uint32_t* cnt = (uint32_t*)alloc(BB * 4);
    uint32_t* ncount = (uint32_t*)alloc(BB * 4);
    uint32_t* ndone = (uint32_t*)alloc(BB * 4);
    uint64_t* cand = (uint64_t*)alloc((size_t)BB * CAND_CAP * 8);          // 512 KB
    uint64_t* cand2 = (uint64_t*)alloc((size_t)BB * CAND_CAP * 8);         // 512 KB
    float4* boxes = (float4*)alloc((size_t)BB * KPAD2 * 16);               // 768 KB
    float* scoresS = (float*)alloc((size_t)BB * KPAD2 * 4);
    float* areas = (float*)alloc((size_t)BB * KPAD2 * 4);
    uint32_t* gsel = (uint32_t*)alloc((size_t)BB * 1024 * 4);              // 32 KB
    uint64_t* diag = (uint64_t*)alloc((size_t)BB * DIAG_U64_PB * 8);       // 1.57 MB
    uint64_t* mat = (uint64_t*)alloc((size_t)BB * MAT_U64_PB * 8);         // 18.1 MB

    if (off > ws_size) {
        hipMemsetAsync(d_out, 0, (size_t)out_size * 4, stream);
        return;
    }

    k_zero<<<BB, 256, 0, stream>>>(ghist, cnt, ncount, ndone);

    k_hist<<<BB * BPB, 256, 0, stream>>>(probs, ghist);
    k_compact<<<BB * BPB, 256, 0, stream>>>(probs, ghist, cnt, cand);
    dim3 gs1(8, BB);
    k_sort1<<<gs1, 512, 0, stream>>>(cnt, cand);
    dim3 gmg(32, BB);
    k_merge<<<gmg, 256, 0, stream>>>(1024, cand, cand2);
    k_merge<<<gmg, 256, 0, stream>>>(2048, cand2, cand);
    dim3 gmd(24, BB);   // 24*256 = 6144 ranks materialized
    k_merge_decode<<<gmd, 256, 0, stream>>>(cand, rpn_bbox, anchors, boxes, scoresS, areas);

    const int cb[3] = {0, 6, 24};
    for (int c = 0; c < 2; ++c) {
        int w0 = cb[c], w1 = cb[c + 1];
        int nblk = 0;
        for (int W = w0; W < w1; ++W) nblk += W + 1;
        dim3 gm(nblk * 2, BB);   // x2: column-half split
        k_matc<<<gm, 256, 0, stream>>>(w0, boxes, areas, mat, diag, ndone);
        k_nms_chunk<<<BB, 256, 0, stream>>>(w0, w1, (w1 == NW2) ? 1 : 0,
                                            boxes, scoresS, diag, mat,
                                            gsel, ncount, ndone, out);
    }
}